// Round 1
// baseline (255.780 us; speedup 1.0000x reference)
//
#include <hip/hip_runtime.h>
#include <math.h>

#define B_    512
#define V_    6890
#define J_    24
#define NB_   10
#define K_    207     // 9*(J-1)
#define KPAD  224
#define TB    64      // batch tile
#define TV    64      // vertex tile
#define KC    32      // K chunk

__constant__ int c_par[24] = {-1,0,0,0,1,2,3,4,5,6,7,8,9,9,9,12,13,14,16,17,18,19,20,21};
__constant__ int c_lev[24] = { 0,1,1,1,2,2,2,3,3,3,4,4,4,4,4, 5, 5, 5, 6, 6, 7, 7, 8, 8};

// ---------------------------------------------------------------------------
// K1: JT[j][k] = sum_v Jreg[j][v]*vt[v][k];  JS[j][k][l] = sum_v Jreg[j][v]*sd[v][k][l]
// grid = 72 (j*3+k), block = 256
// ---------------------------------------------------------------------------
__global__ __launch_bounds__(256) void k_jreg(const float* __restrict__ Jreg,
                                              const float* __restrict__ vt,
                                              const float* __restrict__ sd,
                                              float* __restrict__ JS,
                                              float* __restrict__ JT)
{
    const int j = blockIdx.x / 3, k = blockIdx.x % 3;
    const int tid = threadIdx.x;
    float acc[11];
#pragma unroll
    for (int i = 0; i < 11; ++i) acc[i] = 0.f;

    for (int v = tid; v < V_; v += 256) {
        const float r = Jreg[j * V_ + v];
        acc[0] = fmaf(r, vt[v * 3 + k], acc[0]);
        const float* s = &sd[(v * 3 + k) * NB_];
#pragma unroll
        for (int l = 0; l < NB_; ++l) acc[1 + l] = fmaf(r, s[l], acc[1 + l]);
    }

    __shared__ float red[4][11];
    const int lane = tid & 63, w = tid >> 6;
#pragma unroll
    for (int i = 0; i < 11; ++i) {
        float a = acc[i];
        for (int off = 32; off; off >>= 1) a += __shfl_xor(a, off, 64);
        acc[i] = a;
    }
    if (lane == 0) {
#pragma unroll
        for (int i = 0; i < 11; ++i) red[w][i] = acc[i];
    }
    __syncthreads();
    if (tid == 0) {
        for (int i = 0; i < 11; ++i) {
            const float s = red[0][i] + red[1][i] + red[2][i] + red[3][i];
            if (i == 0) JT[j * 3 + k] = s;
            else        JS[(j * 3 + k) * NB_ + (i - 1)] = s;
        }
    }
}

// ---------------------------------------------------------------------------
// K2: per-batch joint pipeline. grid = 512, block = 64.
// Writes pose_feature [B][KPAD] (zero padded), A [B][24][12], joints output.
// ---------------------------------------------------------------------------
__global__ __launch_bounds__(64) void k_pose(const float* __restrict__ betas,
                                             const float* __restrict__ body_pose,
                                             const float* __restrict__ global_orient,
                                             const float* __restrict__ transl,
                                             const float* __restrict__ JS,
                                             const float* __restrict__ JT,
                                             float* __restrict__ Aout,
                                             float* __restrict__ pfout,
                                             float* __restrict__ joints_out)
{
    const int b = blockIdx.x;
    const int j = threadIdx.x;

    __shared__ float sR[24][9];
    __shared__ float sJ[24][3];
    __shared__ float sTl[24][12];
    __shared__ float sTg[24][12];

    if (j < 24) {
        float rx, ry, rz;
        if (j == 0) {
            rx = global_orient[b * 3 + 0];
            ry = global_orient[b * 3 + 1];
            rz = global_orient[b * 3 + 2];
        } else {
            const float* p = &body_pose[b * 69 + (j - 1) * 3];
            rx = p[0]; ry = p[1]; rz = p[2];
        }
        // reference: angle = norm(rv + 1e-8) (added per-component), axis = rv/angle
        const float ax = rx + 1e-8f, ay = ry + 1e-8f, az = rz + 1e-8f;
        const float angle = sqrtf(ax * ax + ay * ay + az * az);
        const float inv = 1.f / angle;
        const float x = rx * inv, y = ry * inv, z = rz * inv;
        const float s = sinf(angle), c = cosf(angle), t = 1.f - c;

        float R[9];
        R[0] = 1.f - t * (y * y + z * z);
        R[1] = -s * z + t * x * y;
        R[2] =  s * y + t * x * z;
        R[3] =  s * z + t * x * y;
        R[4] = 1.f - t * (x * x + z * z);
        R[5] = -s * x + t * y * z;
        R[6] = -s * y + t * x * z;
        R[7] =  s * x + t * y * z;
        R[8] = 1.f - t * (x * x + y * y);

#pragma unroll
        for (int e = 0; e < 9; ++e) sR[j][e] = R[e];

        if (j >= 1) {
#pragma unroll
            for (int e = 0; e < 9; ++e) {
                const float id = (e == 0 || e == 4 || e == 8) ? 1.f : 0.f;
                pfout[b * KPAD + (j - 1) * 9 + e] = R[e] - id;
            }
        }
        // Jrest
#pragma unroll
        for (int k = 0; k < 3; ++k) {
            float jr = JT[j * 3 + k];
#pragma unroll
            for (int l = 0; l < NB_; ++l)
                jr = fmaf(betas[b * NB_ + l], JS[(j * 3 + k) * NB_ + l], jr);
            sJ[j][k] = jr;
        }
    }
    if (j >= 24 && j < 24 + (KPAD - K_)) pfout[b * KPAD + K_ + (j - 24)] = 0.f;
    __syncthreads();

    if (j < 24) {
        const int p = c_par[j];
        float t0 = sJ[j][0], t1 = sJ[j][1], t2 = sJ[j][2];
        if (j > 0) { t0 -= sJ[p][0]; t1 -= sJ[p][1]; t2 -= sJ[p][2]; }
        sTl[j][0] = sR[j][0]; sTl[j][1] = sR[j][1]; sTl[j][2]  = sR[j][2]; sTl[j][3]  = t0;
        sTl[j][4] = sR[j][3]; sTl[j][5] = sR[j][4]; sTl[j][6]  = sR[j][5]; sTl[j][7]  = t1;
        sTl[j][8] = sR[j][6]; sTl[j][9] = sR[j][7]; sTl[j][10] = sR[j][8]; sTl[j][11] = t2;
    }
    __syncthreads();

    if (j == 0) {
#pragma unroll
        for (int e = 0; e < 12; ++e) sTg[0][e] = sTl[0][e];
    }
    __syncthreads();

    for (int lev = 1; lev <= 8; ++lev) {
        if (j < 24 && c_lev[j] == lev) {
            const int p = c_par[j];
            float o[12];
#pragma unroll
            for (int r = 0; r < 3; ++r) {
#pragma unroll
                for (int c = 0; c < 4; ++c) {
                    float v = (c == 3) ? sTg[p][r * 4 + 3] : 0.f;
#pragma unroll
                    for (int m = 0; m < 3; ++m)
                        v = fmaf(sTg[p][r * 4 + m], sTl[j][m * 4 + c], v);
                    o[r * 4 + c] = v;
                }
            }
#pragma unroll
            for (int e = 0; e < 12; ++e) sTg[j][e] = o[e];
        }
        __syncthreads();
    }

    if (j < 24) {
        float corr[3];
#pragma unroll
        for (int r = 0; r < 3; ++r)
            corr[r] = sTg[j][r * 4 + 0] * sJ[j][0] + sTg[j][r * 4 + 1] * sJ[j][1]
                    + sTg[j][r * 4 + 2] * sJ[j][2];
        float* Ab = &Aout[(b * 24 + j) * 12];
#pragma unroll
        for (int r = 0; r < 3; ++r) {
            Ab[r * 4 + 0] = sTg[j][r * 4 + 0];
            Ab[r * 4 + 1] = sTg[j][r * 4 + 1];
            Ab[r * 4 + 2] = sTg[j][r * 4 + 2];
            Ab[r * 4 + 3] = sTg[j][r * 4 + 3] - corr[r];
        }
#pragma unroll
        for (int k = 0; k < 3; ++k)
            joints_out[(b * 24 + j) * 3 + k] = sTg[j][k * 4 + 3] + transl[b * 3 + k];
    }
}

// ---------------------------------------------------------------------------
// K3: fused pose-blend GEMM + shape blend + LBS + write vertices.
// grid = (ceil(V/TV)=108, B/TB=8), block = 256.
// thread micro-tile: 4b x 4v (tb = tid>>4 -> 4 batches, tv = tid&15 -> 4 verts)
// ---------------------------------------------------------------------------
__global__ __launch_bounds__(256) void k_verts(const float* __restrict__ betas,
                                               const float* __restrict__ v_template,
                                               const float* __restrict__ shapedirs,
                                               const float* __restrict__ posedirs,
                                               const float* __restrict__ lbs_weights,
                                               const float* __restrict__ transl,
                                               const float* __restrict__ pf,   // [B][KPAD]
                                               const float* __restrict__ A,    // [B][24][12]
                                               float* __restrict__ out)        // [B][V][3]
{
    __shared__ __align__(16) float s_pd[KC][TV * 3];   // 24 KB
    __shared__ float s_pf[TB][KC + 1];                 // 8.4 KB
    __shared__ float s_w[TV][25];                      // 6.4 KB (pad 25 vs 16-way conflict)
    __shared__ float s_betas[TB][NB_];                 // 2.5 KB

    const int vtile = blockIdx.x, btile = blockIdx.y;
    const int vbase = vtile * TV, bbase = btile * TB;
    const int tid = threadIdx.x;
    const int tb = tid >> 4;        // 0..15 -> 4 batches each
    const int tv = tid & 15;        // 0..15 -> 4 verts each

    // stage lbs weights and betas (read once per block)
    for (int i = tid; i < TV * 24; i += 256) {
        const int vl = i / 24, jj = i % 24;
        const int v = vbase + vl;
        s_w[vl][jj] = (v < V_) ? lbs_weights[v * 24 + jj] : 0.f;
    }
    for (int i = tid; i < TB * NB_; i += 256)
        s_betas[i / NB_][i % NB_] = betas[(bbase + i / NB_) * NB_ + i % NB_];

    float acc[4][4][3];
#pragma unroll
    for (int bi = 0; bi < 4; ++bi)
#pragma unroll
        for (int vi = 0; vi < 4; ++vi)
#pragma unroll
            for (int k = 0; k < 3; ++k) acc[bi][vi][k] = 0.f;

    // ---- phase 1: pose-blend GEMM, K chunks of 32 ----
    for (int kc = 0; kc < KPAD; kc += KC) {
        __syncthreads();
        // stage pf tile: TB x KC
        for (int i = tid; i < TB * KC; i += 256) {
            const int bl = i / KC, kk = i % KC;
            s_pf[bl][kk] = pf[(bbase + bl) * KPAD + kc + kk];   // pad region is zeroed
        }
        // stage posedirs tile: KC rows x 192 cols
        for (int i = tid; i < KC * (TV * 3); i += 256) {
            const int r = i / (TV * 3), c = i % (TV * 3);
            const int gk = kc + r, gc = vbase * 3 + c;
            s_pd[r][c] = (gk < K_ && gc < V_ * 3) ? posedirs[gk * (V_ * 3) + gc] : 0.f;
        }
        __syncthreads();

        for (int kk = 0; kk < KC; ++kk) {
            float pfr[4];
#pragma unroll
            for (int bi = 0; bi < 4; ++bi) pfr[bi] = s_pf[tb * 4 + bi][kk];
            const float4* p4 = reinterpret_cast<const float4*>(&s_pd[kk][tv * 12]);
            const float4 pa = p4[0], pb = p4[1], pc = p4[2];
            const float pdr[12] = {pa.x, pa.y, pa.z, pa.w, pb.x, pb.y, pb.z, pb.w,
                                   pc.x, pc.y, pc.z, pc.w};
#pragma unroll
            for (int bi = 0; bi < 4; ++bi)
#pragma unroll
                for (int vi = 0; vi < 4; ++vi)
#pragma unroll
                    for (int k = 0; k < 3; ++k)
                        acc[bi][vi][k] = fmaf(pfr[bi], pdr[vi * 3 + k], acc[bi][vi][k]);
        }
    }
    __syncthreads();

    // ---- phase 2: add v_shaped = v_template + shapedirs @ betas ----
#pragma unroll
    for (int vi = 0; vi < 4; ++vi) {
        const int v = vbase + tv * 4 + vi;
        if (v >= V_) continue;
        float vt[3], sd[30];
#pragma unroll
        for (int k = 0; k < 3; ++k) vt[k] = v_template[v * 3 + k];
#pragma unroll
        for (int i = 0; i < 30; ++i) sd[i] = shapedirs[v * 30 + i];
#pragma unroll
        for (int bi = 0; bi < 4; ++bi) {
            const int bl = tb * 4 + bi;
#pragma unroll
            for (int k = 0; k < 3; ++k) {
                float vs = vt[k];
#pragma unroll
                for (int l = 0; l < NB_; ++l)
                    vs = fmaf(s_betas[bl][l], sd[k * NB_ + l], vs);
                acc[bi][vi][k] += vs;
            }
        }
    }

    // ---- phase 3: LBS — transform per joint, weighted sum ----
    float vert[4][4][3];
#pragma unroll
    for (int bi = 0; bi < 4; ++bi)
#pragma unroll
        for (int vi = 0; vi < 4; ++vi)
#pragma unroll
            for (int k = 0; k < 3; ++k) vert[bi][vi][k] = 0.f;

    for (int j = 0; j < 24; ++j) {
        float wv[4];
#pragma unroll
        for (int vi = 0; vi < 4; ++vi) wv[vi] = s_w[tv * 4 + vi][j];
#pragma unroll
        for (int bi = 0; bi < 4; ++bi) {
            const int b = bbase + tb * 4 + bi;
            const float4* Ap = reinterpret_cast<const float4*>(&A[(b * 24 + j) * 12]);
            const float4 r0 = Ap[0], r1 = Ap[1], r2 = Ap[2];
#pragma unroll
            for (int vi = 0; vi < 4; ++vi) {
                const float x = acc[bi][vi][0], y = acc[bi][vi][1], z = acc[bi][vi][2];
                const float txv = fmaf(r0.x, x, fmaf(r0.y, y, fmaf(r0.z, z, r0.w)));
                const float tyv = fmaf(r1.x, x, fmaf(r1.y, y, fmaf(r1.z, z, r1.w)));
                const float tzv = fmaf(r2.x, x, fmaf(r2.y, y, fmaf(r2.z, z, r2.w)));
                vert[bi][vi][0] = fmaf(wv[vi], txv, vert[bi][vi][0]);
                vert[bi][vi][1] = fmaf(wv[vi], tyv, vert[bi][vi][1]);
                vert[bi][vi][2] = fmaf(wv[vi], tzv, vert[bi][vi][2]);
            }
        }
    }

    // ---- write ----
#pragma unroll
    for (int bi = 0; bi < 4; ++bi) {
        const int b = bbase + tb * 4 + bi;
        const float t0 = transl[b * 3 + 0], t1 = transl[b * 3 + 1], t2 = transl[b * 3 + 2];
#pragma unroll
        for (int vi = 0; vi < 4; ++vi) {
            const int v = vbase + tv * 4 + vi;
            if (v < V_) {
                float* o = &out[(b * (size_t)V_ + v) * 3];
                o[0] = vert[bi][vi][0] + t0;
                o[1] = vert[bi][vi][1] + t1;
                o[2] = vert[bi][vi][2] + t2;
            }
        }
    }
}

// ---------------------------------------------------------------------------
extern "C" void kernel_launch(void* const* d_in, const int* in_sizes, int n_in,
                              void* d_out, int out_size, void* d_ws, size_t ws_size,
                              hipStream_t stream)
{
    const float* betas         = (const float*)d_in[0];
    const float* body_pose     = (const float*)d_in[1];
    const float* global_orient = (const float*)d_in[2];
    const float* transl        = (const float*)d_in[3];
    const float* v_template    = (const float*)d_in[4];
    const float* shapedirs     = (const float*)d_in[5];
    const float* posedirs      = (const float*)d_in[6];
    const float* J_regressor   = (const float*)d_in[7];
    const float* lbs_weights   = (const float*)d_in[8];

    float* out = (float*)d_out;
    float* ws  = (float*)d_ws;

    // workspace layout (floats): JS[720] | JT[72] | A[512*24*12] | pf[512*224]
    float* JS  = ws;
    float* JT  = ws + 720;
    float* Aw  = ws + 792;
    float* pfw = ws + 792 + (size_t)B_ * 24 * 12;

    float* joints = out + (size_t)B_ * V_ * 3;

    k_jreg <<<72, 256, 0, stream>>>(J_regressor, v_template, shapedirs, JS, JT);
    k_pose <<<B_, 64, 0, stream>>>(betas, body_pose, global_orient, transl,
                                   JS, JT, Aw, pfw, joints);
    dim3 g3((V_ + TV - 1) / TV, B_ / TB);
    k_verts<<<g3, 256, 0, stream>>>(betas, v_template, shapedirs, posedirs,
                                    lbs_weights, transl, pfw, Aw, out);
}